// Round 10
// baseline (156.138 us; speedup 1.0000x reference)
//
#include <hip/hip_runtime.h>

#define KTOP 100
#define NCOL 16384
#define TPB  1024
#define RPB  8                   // rows per block; grid = 4096/8 = 512 -> 2 blocks/CU
#define HST  520                 // per-copy hist stride (512 words + 8 pad)
#define CAPB 512                 // boundary-bin candidate capacity
#define T0K  0xC0000000u         // enc(+2.0f)
#define BIN0 1536u               // T0K >> 21

// order-preserving key transform: a<b (float) <=> enc(a)<enc(b) (uint)
__device__ __forceinline__ unsigned enc(unsigned u){ return u ^ (((unsigned)((int)u>>31)) | 0x80000000u); }
__device__ __forceinline__ unsigned dec(unsigned k){ return k ^ ((k & 0x80000000u) ? 0x80000000u : 0xFFFFFFFFu); }
// transposed hist word index: lane's 8 bins land at stride-64 words -> conflict-free scan
__device__ __forceinline__ int hw(unsigned b){ return (int)(((b & 7u) << 6) | (b >> 3)); }

__global__ __launch_bounds__(TPB, 8)
void topk_act_kernel(const float* __restrict__ x, float* __restrict__ out, int nrow_total) {
    __shared__ unsigned hist[2][2*HST];   // double-buffered, 2 wave-group copies each (8.3 KB)
    __shared__ unsigned cand[CAPB];       // boundary-bin candidates / generic-path 256-bin scratch
    __shared__ unsigned s_pos[2];
    __shared__ unsigned s_cnt;
    __shared__ unsigned s_T, s_krem, s_eqc;

    const int tid = threadIdx.x, lane = tid & 63, wv = tid >> 6;
    const int row0 = blockIdx.x * RPB;
    const int nrows = (nrow_total - row0 < RPB) ? (nrow_total - row0) : RPB;
    if (nrows <= 0) return;

    uint4 vA[4], vB[4];

    // ---- prologue: zero buf0, load row 0 -> vA, hist(>=2.0) ----
    for (int i = tid; i < 2*HST; i += TPB) hist[0][i] = 0;
    if (tid == 0) { s_pos[0] = 0; s_cnt = 0; }
    __syncthreads();
    {
        const uint4* xr = (const uint4*)(x + (size_t)row0 * NCOL);
        vA[0]=xr[tid]; vA[1]=xr[tid+TPB]; vA[2]=xr[tid+2*TPB]; vA[3]=xr[tid+3*TPB];
        unsigned* hb = hist[0] + (wv&1)*HST;
        unsigned pc = 0;
        #pragma unroll
        for (int j = 0; j < 4; ++j) {
            vA[j].x=enc(vA[j].x); vA[j].y=enc(vA[j].y); vA[j].z=enc(vA[j].z); vA[j].w=enc(vA[j].w);
            if (vA[j].x>=T0K){ atomicAdd(&hb[hw((vA[j].x>>21)-BIN0)],1u); ++pc; }
            if (vA[j].y>=T0K){ atomicAdd(&hb[hw((vA[j].y>>21)-BIN0)],1u); ++pc; }
            if (vA[j].z>=T0K){ atomicAdd(&hb[hw((vA[j].z>>21)-BIN0)],1u); ++pc; }
            if (vA[j].w>=T0K){ atomicAdd(&hb[hw((vA[j].w>>21)-BIN0)],1u); ++pc; }
        }
        #pragma unroll
        for (int s = 1; s < 64; s <<= 1) pc += __shfl_down(pc, s);
        if (lane == 0) atomicAdd(&s_pos[0], pc);
    }
    __syncthreads();

    auto step = [&](uint4 (&VC)[4], uint4 (&VN)[4], int r) {
        if (r >= nrows) return;
        const int cb = r & 1, nb = cb ^ 1;
        // ---- B: zero next hist; select row r ----
        for (int i = tid; i < 2*HST; i += TPB) hist[nb][i] = 0;
        if (tid == 0) s_pos[nb] = 0;
        const unsigned pos = s_pos[cb];
        bool ngen = false;
        if (pos >= KTOP) {
            // wave-redundant suffix scan of 512 dual-copy bins (transposed layout)
            unsigned own = 0;
            #pragma unroll
            for (int w = 0; w < 8; ++w) own += hist[cb][64*w + lane] + hist[cb][HST + 64*w + lane];
            unsigned incl = own;
            #pragma unroll
            for (int s = 1; s < 64; s <<= 1) { unsigned t = __shfl_down(incl, s); if (lane + s < 64) incl += t; }
            const unsigned above = incl - own;
            bool hit = (above < KTOP) && (above + own >= KTOP);
            unsigned long long bal = __ballot(hit);
            int L = __ffsll((long long)bal) - 1;
            unsigned run = __shfl(above, L);
            unsigned sbin = 0, sk = 1, se = 1;
            for (int w = 7; w >= 0; --w) {
                unsigned c = hist[cb][64*w + L] + hist[cb][HST + 64*w + L];
                unsigned rr = run + c;
                if (run < KTOP && rr >= KTOP) { sbin = 8u*(unsigned)L + (unsigned)w; sk = KTOP - run; se = c; }
                run = rr;
            }
            const unsigned pbin = sbin + BIN0;
            if (sk == se) {
                if (tid == 0) { s_T = pbin << 21; s_krem = sk; s_eqc = se; }   // whole bin kept
            } else {
                // extract boundary-bin candidates from registers (~20-80 per row)
                #pragma unroll
                for (int j = 0; j < 4; ++j) {
                    if ((VC[j].x >> 21) == pbin) { unsigned i = atomicAdd(&s_cnt,1u); if (i < CAPB) cand[i] = VC[j].x; }
                    if ((VC[j].y >> 21) == pbin) { unsigned i = atomicAdd(&s_cnt,1u); if (i < CAPB) cand[i] = VC[j].y; }
                    if ((VC[j].z >> 21) == pbin) { unsigned i = atomicAdd(&s_cnt,1u); if (i < CAPB) cand[i] = VC[j].z; }
                    if ((VC[j].w >> 21) == pbin) { unsigned i = atomicAdd(&s_cnt,1u); if (i < CAPB) cand[i] = VC[j].w; }
                }
                __syncthreads();
                const unsigned mcnt = s_cnt;
                if (mcnt <= CAPB) {
                    if (tid < (int)mcnt) {       // all-pairs rank (LDS broadcast reads)
                        const unsigned c = cand[tid];
                        unsigned g = 0, q = 0;
                        for (unsigned jj = 0; jj < mcnt; ++jj) { unsigned cj = cand[jj]; g += (cj > c); q += (cj == c); }
                        if (g < sk && g + q >= sk) { s_T = c; s_krem = sk - g; s_eqc = q; }
                    }
                } else ngen = true;
            }
        } else ngen = true;
        if (ngen) {
            // rare generic 4x8-bit radix select from registers (any distribution)
            unsigned pref = 0, kc = KTOP, eq = 0;
            for (int p = 0; p < 4; ++p) {
                const int shift = 24 - 8*p;
                __syncthreads();
                for (int i = tid; i < 256; i += TPB) cand[i] = 0;
                __syncthreads();
                #pragma unroll
                for (int j = 0; j < 4; ++j) {
                    unsigned kk;
                    kk = VC[j].x; if (p == 0 || ((kk ^ pref) >> (shift+8)) == 0) atomicAdd(&cand[(kk >> shift) & 0xFFu], 1u);
                    kk = VC[j].y; if (p == 0 || ((kk ^ pref) >> (shift+8)) == 0) atomicAdd(&cand[(kk >> shift) & 0xFFu], 1u);
                    kk = VC[j].z; if (p == 0 || ((kk ^ pref) >> (shift+8)) == 0) atomicAdd(&cand[(kk >> shift) & 0xFFu], 1u);
                    kk = VC[j].w; if (p == 0 || ((kk ^ pref) >> (shift+8)) == 0) atomicAdd(&cand[(kk >> shift) & 0xFFu], 1u);
                }
                __syncthreads();
                unsigned t0 = cand[4*lane], t1 = cand[4*lane+1], t2 = cand[4*lane+2], t3 = cand[4*lane+3];
                unsigned own = t0+t1+t2+t3, incl = own;
                #pragma unroll
                for (int s = 1; s < 64; s <<= 1) { unsigned t = __shfl_down(incl, s); if (lane + s < 64) incl += t; }
                unsigned above = incl - own;
                unsigned C3 = above + t3, C2 = C3 + t2, C1 = C2 + t1, C0 = C1 + t0;
                bool h3 = (above < kc) && (C3 >= kc);
                bool h2 = (C3 < kc) && (C2 >= kc);
                bool h1 = (C2 < kc) && (C1 >= kc);
                bool h0 = (C1 < kc) && (C0 >= kc);
                unsigned mybin = h3 ? (4u*lane+3u) : h2 ? (4u*lane+2u) : h1 ? (4u*lane+1u) : (4u*lane);
                unsigned myk   = h3 ? (kc - above) : h2 ? (kc - C3) : h1 ? (kc - C2) : (kc - C1);
                unsigned myeq  = h3 ? t3 : h2 ? t2 : h1 ? t1 : t0;
                unsigned long long bal2 = __ballot(h0|h1|h2|h3);
                int L2 = __ffsll((long long)bal2) - 1;
                pref |= __shfl(mybin, L2) << shift;
                kc    = __shfl(myk, L2);
                eq    = __shfl(myeq, L2);
            }
            if (tid == 0) { s_T = pref; s_krem = kc; s_eqc = eq; }
        }
        __syncthreads();                        // publish + zero-fence
        if (tid == 0) s_cnt = 0;                // safe reset (no reader until next B)
        const unsigned T = s_T, krem = s_krem, eqv = s_eqc;

        // ---- A: memory phase — store row r, then load row r+1 (all issued before waits) ----
        uint4* orow = (uint4*)(out + (size_t)(row0 + r) * NCOL);
        if (krem == eqv) {
            #pragma unroll
            for (int j = 0; j < 4; ++j) {
                uint4 o;
                o.x = (VC[j].x >= T) ? dec(VC[j].x) : 0u;
                o.y = (VC[j].y >= T) ? dec(VC[j].y) : 0u;
                o.z = (VC[j].z >= T) ? dec(VC[j].z) : 0u;
                o.w = (VC[j].w >= T) ? dec(VC[j].w) : 0u;
                orow[tid + j*TPB] = o;
            }
        } else {
            // ultra-rare stable tie: block scan (hist[cb] is dead -> scan space)
            unsigned* sa = hist[cb];
            unsigned runacc = 0;
            for (int j = 0; j < 4; ++j) {
                unsigned e0=(VC[j].x==T), e1=(VC[j].y==T), e2=(VC[j].z==T), e3=(VC[j].w==T);
                unsigned le = e0+e1+e2+e3;
                __syncthreads();
                sa[tid] = le;
                __syncthreads();
                for (int s = 1; s < TPB; s <<= 1) {
                    unsigned t = (tid >= s) ? sa[tid-s] : 0u;
                    __syncthreads();
                    sa[tid] += t;
                    __syncthreads();
                }
                unsigned excl = sa[tid] - le, total = sa[TPB-1];
                unsigned r0 = runacc + excl, r1 = r0+e0, r2 = r1+e1, r3 = r2+e2;
                uint4 o;
                o.x = (VC[j].x > T || (e0 && r0 < krem)) ? dec(VC[j].x) : 0u;
                o.y = (VC[j].y > T || (e1 && r1 < krem)) ? dec(VC[j].y) : 0u;
                o.z = (VC[j].z > T || (e2 && r2 < krem)) ? dec(VC[j].z) : 0u;
                o.w = (VC[j].w > T || (e3 && r3 < krem)) ? dec(VC[j].w) : 0u;
                orow[tid + j*TPB] = o;
                runacc += total;
            }
        }
        if (r + 1 < nrows) {
            const uint4* xr = (const uint4*)(x + (size_t)(row0 + r + 1) * NCOL);
            VN[0]=xr[tid]; VN[1]=xr[tid+TPB]; VN[2]=xr[tid+2*TPB]; VN[3]=xr[tid+3*TPB];
            unsigned* hb = hist[nb] + (wv&1)*HST;
            unsigned pc = 0;
            #pragma unroll
            for (int j = 0; j < 4; ++j) {
                VN[j].x=enc(VN[j].x); VN[j].y=enc(VN[j].y); VN[j].z=enc(VN[j].z); VN[j].w=enc(VN[j].w);
                if (VN[j].x>=T0K){ atomicAdd(&hb[hw((VN[j].x>>21)-BIN0)],1u); ++pc; }
                if (VN[j].y>=T0K){ atomicAdd(&hb[hw((VN[j].y>>21)-BIN0)],1u); ++pc; }
                if (VN[j].z>=T0K){ atomicAdd(&hb[hw((VN[j].z>>21)-BIN0)],1u); ++pc; }
                if (VN[j].w>=T0K){ atomicAdd(&hb[hw((VN[j].w>>21)-BIN0)],1u); ++pc; }
            }
            #pragma unroll
            for (int s = 1; s < 64; s <<= 1) pc += __shfl_down(pc, s);
            if (lane == 0) atomicAdd(&s_pos[nb], pc);
        }
        __syncthreads();                        // A-end: hist[nb]/s_pos[nb] complete
    };

    for (int rp = 0; rp < RPB; rp += 2) {
        step(vA, vB, rp);
        step(vB, vA, rp + 1);
    }
}

extern "C" void kernel_launch(void* const* d_in, const int* in_sizes, int n_in,
                              void* d_out, int out_size, void* d_ws, size_t ws_size,
                              hipStream_t stream) {
    const float* x = (const float*)d_in[0];
    float* out = (float*)d_out;
    const int B = in_sizes[0] / NCOL;   // 4096 rows
    const int grid = (B + RPB - 1) / RPB;
    topk_act_kernel<<<grid, TPB, 0, stream>>>(x, out, B);
}

// Round 11
// 145.835 us; speedup vs baseline: 1.0707x; 1.0707x over previous
//
#include <hip/hip_runtime.h>

#define KTOP 100
#define NCOL 16384
#define TPB  512
#define NCHUNK 8                 // 8 float4 (32 values) per thread, in registers
#define HST  520                 // per-copy hist stride (512 words + 8 pad)
#define CAPB 512                 // boundary-bin candidate capacity
#define RB0  512u                // __float_as_uint(2.0f) >> 21

// order-preserving key transform (rare fallback paths only)
__device__ __forceinline__ unsigned enc(unsigned u){ return u ^ (((unsigned)((int)u>>31)) | 0x80000000u); }
__device__ __forceinline__ unsigned dec(unsigned k){ return k ^ ((k & 0x80000000u) ? 0x80000000u : 0xFFFFFFFFu); }
// transposed hist word index: scan reads are stride-64 words -> conflict-free
__device__ __forceinline__ int hw(unsigned b){ return (int)(((b & 7u) << 6) | (b >> 3)); }

__global__ __launch_bounds__(TPB, 8)
void topk_act_kernel(const float* __restrict__ x, float* __restrict__ out) {
    __shared__ unsigned hist[2*HST];     // 2 wave-group copies (4.2 KB); tie path reuses as scan space
    __shared__ unsigned cand[CAPB];      // candidates / generic-path 256-bin hist
    __shared__ unsigned s_pos, s_cnt, s_T, s_krem, s_eqc;

    const int tid = threadIdx.x, lane = tid & 63, wv = tid >> 6;
    const int row = blockIdx.x;
    const float4* __restrict__ xr = (const float4*)(x + (size_t)row * NCOL);
    float4* __restrict__ orow = (float4*)(out + (size_t)row * NCOL);

    for (int i = tid; i < 2*HST; i += TPB) hist[i] = 0;
    if (tid == 0) { s_pos = 0; s_cnt = 0; }
    __syncthreads();

    // ---- single HBM read -> registers (raw floats); hist only values >= 2.0 (~373/row) ----
    float4 v[NCHUNK];
    unsigned* hb = hist + (wv & 1) * HST;
    unsigned pc = 0;
    #pragma unroll
    for (int j = 0; j < NCHUNK; ++j) {
        v[j] = xr[tid + j*TPB];
        if (v[j].x >= 2.0f) { atomicAdd(&hb[hw((__float_as_uint(v[j].x)>>21)-RB0)],1u); ++pc; }
        if (v[j].y >= 2.0f) { atomicAdd(&hb[hw((__float_as_uint(v[j].y)>>21)-RB0)],1u); ++pc; }
        if (v[j].z >= 2.0f) { atomicAdd(&hb[hw((__float_as_uint(v[j].z)>>21)-RB0)],1u); ++pc; }
        if (v[j].w >= 2.0f) { atomicAdd(&hb[hw((__float_as_uint(v[j].w)>>21)-RB0)],1u); ++pc; }
    }
    #pragma unroll
    for (int s = 1; s < 64; s <<= 1) pc += __shfl_down(pc, s);
    if (lane == 0) atomicAdd(&s_pos, pc);
    __syncthreads();

    bool ngen = false;
    if (s_pos >= KTOP) {
        // ---- wave-redundant suffix scan of 512 dual-copy bins (transposed layout) ----
        unsigned own = 0;
        #pragma unroll
        for (int w = 0; w < 8; ++w) own += hist[64*w + lane] + hist[HST + 64*w + lane];
        unsigned incl = own;
        #pragma unroll
        for (int s = 1; s < 64; s <<= 1) { unsigned t = __shfl_down(incl, s); if (lane + s < 64) incl += t; }
        const unsigned above = incl - own;
        bool hit = (above < KTOP) && (above + own >= KTOP);
        unsigned long long bal = __ballot(hit);
        int L = __ffsll((long long)bal) - 1;
        unsigned run = __shfl(above, L);
        unsigned sbin = 0, sk = 1, se = 1;
        for (int w = 7; w >= 0; --w) {
            unsigned c = hist[64*w + L] + hist[HST + 64*w + L];
            unsigned rr = run + c;
            if (run < KTOP && rr >= KTOP) { sbin = 8u*(unsigned)L + (unsigned)w; sk = KTOP - run; se = c; }
            run = rr;
        }
        const unsigned pbin = sbin + RB0;           // raw-bits bin (bits>>21) of boundary
        if (sk == se) {
            if (tid == 0) { s_T = pbin << 21; s_krem = sk; s_eqc = se; }   // keep whole bin
        } else {
            // extract boundary-bin candidates (raw bits; positives -> uint order == float order)
            #pragma unroll
            for (int j = 0; j < NCHUNK; ++j) {
                if ((__float_as_uint(v[j].x)>>21) == pbin) { unsigned i = atomicAdd(&s_cnt,1u); if (i < CAPB) cand[i] = __float_as_uint(v[j].x); }
                if ((__float_as_uint(v[j].y)>>21) == pbin) { unsigned i = atomicAdd(&s_cnt,1u); if (i < CAPB) cand[i] = __float_as_uint(v[j].y); }
                if ((__float_as_uint(v[j].z)>>21) == pbin) { unsigned i = atomicAdd(&s_cnt,1u); if (i < CAPB) cand[i] = __float_as_uint(v[j].z); }
                if ((__float_as_uint(v[j].w)>>21) == pbin) { unsigned i = atomicAdd(&s_cnt,1u); if (i < CAPB) cand[i] = __float_as_uint(v[j].w); }
            }
            __syncthreads();
            const unsigned mcnt = s_cnt;
            if (mcnt <= CAPB) {
                if (tid < (int)mcnt) {              // all-pairs rank over ~10-80 candidates
                    const unsigned c = cand[tid];
                    unsigned g = 0, q = 0;
                    for (unsigned jj = 0; jj < mcnt; ++jj) { unsigned cj = cand[jj]; g += (cj > c); q += (cj == c); }
                    if (g < sk && g + q >= sk) { s_T = c; s_krem = sk - g; s_eqc = q; }
                }
            } else ngen = true;
        }
    } else ngen = true;

    if (ngen) {
        // ---- rare generic 4x8-bit radix select (any distribution), enc keys on the fly ----
        unsigned pref = 0, kc = KTOP, eq = 0;
        for (int p = 0; p < 4; ++p) {
            const int shift = 24 - 8*p;
            __syncthreads();
            for (int i = tid; i < 256; i += TPB) cand[i] = 0;
            __syncthreads();
            #pragma unroll
            for (int j = 0; j < NCHUNK; ++j) {
                unsigned kk;
                kk = enc(__float_as_uint(v[j].x)); if (p == 0 || ((kk ^ pref) >> (shift+8)) == 0) atomicAdd(&cand[(kk >> shift) & 0xFFu], 1u);
                kk = enc(__float_as_uint(v[j].y)); if (p == 0 || ((kk ^ pref) >> (shift+8)) == 0) atomicAdd(&cand[(kk >> shift) & 0xFFu], 1u);
                kk = enc(__float_as_uint(v[j].z)); if (p == 0 || ((kk ^ pref) >> (shift+8)) == 0) atomicAdd(&cand[(kk >> shift) & 0xFFu], 1u);
                kk = enc(__float_as_uint(v[j].w)); if (p == 0 || ((kk ^ pref) >> (shift+8)) == 0) atomicAdd(&cand[(kk >> shift) & 0xFFu], 1u);
            }
            __syncthreads();
            unsigned t0 = cand[4*lane], t1 = cand[4*lane+1], t2 = cand[4*lane+2], t3 = cand[4*lane+3];
            unsigned own = t0+t1+t2+t3, incl = own;
            #pragma unroll
            for (int s = 1; s < 64; s <<= 1) { unsigned t = __shfl_down(incl, s); if (lane + s < 64) incl += t; }
            unsigned above = incl - own;
            unsigned C3 = above + t3, C2 = C3 + t2, C1 = C2 + t1, C0 = C1 + t0;
            bool h3 = (above < kc) && (C3 >= kc);
            bool h2 = (C3 < kc) && (C2 >= kc);
            bool h1 = (C2 < kc) && (C1 >= kc);
            bool h0 = (C1 < kc) && (C0 >= kc);
            unsigned mybin = h3 ? (4u*lane+3u) : h2 ? (4u*lane+2u) : h1 ? (4u*lane+1u) : (4u*lane);
            unsigned myk   = h3 ? (kc - above) : h2 ? (kc - C3) : h1 ? (kc - C2) : (kc - C1);
            unsigned myeq  = h3 ? t3 : h2 ? t2 : h1 ? t1 : t0;
            unsigned long long bal2 = __ballot(h0|h1|h2|h3);
            int L2 = __ffsll((long long)bal2) - 1;
            pref |= __shfl(mybin, L2) << shift;
            kc    = __shfl(myk, L2);
            eq    = __shfl(myeq, L2);
        }
        if (tid == 0) { s_T = dec(pref); s_krem = kc; s_eqc = eq; }   // publish as raw float bits
    }
    __syncthreads();                                 // publish fence

    const float fT = __uint_as_float(s_T);
    const unsigned krem = s_krem, eqv = s_eqc;

    if (krem == eqv) {
        // ---- fast path: pure float compare, dense stores from registers ----
        #pragma unroll
        for (int j = 0; j < NCHUNK; ++j) {
            float4 o;
            o.x = (v[j].x >= fT) ? v[j].x : 0.f;
            o.y = (v[j].y >= fT) ? v[j].y : 0.f;
            o.z = (v[j].z >= fT) ? v[j].z : 0.f;
            o.w = (v[j].w >= fT) ? v[j].w : 0.f;
            orow[tid + j*TPB] = o;
        }
    } else {
        // ---- rare stable tie path: keep first krem equals in column order ----
        unsigned* sa = hist;                          // 1040 words >= TPB
        unsigned runacc = 0;
        for (int j = 0; j < NCHUNK; ++j) {
            unsigned e0 = (v[j].x == fT), e1 = (v[j].y == fT), e2 = (v[j].z == fT), e3 = (v[j].w == fT);
            unsigned le = e0+e1+e2+e3;
            __syncthreads();
            sa[tid] = le;
            __syncthreads();
            for (int s = 1; s < TPB; s <<= 1) {
                unsigned t = (tid >= s) ? sa[tid-s] : 0u;
                __syncthreads();
                sa[tid] += t;
                __syncthreads();
            }
            unsigned excl = sa[tid] - le, total = sa[TPB-1];
            unsigned r0 = runacc + excl, r1 = r0+e0, r2 = r1+e1, r3 = r2+e2;
            float4 o;
            o.x = (v[j].x > fT || (e0 && r0 < krem)) ? v[j].x : 0.f;
            o.y = (v[j].y > fT || (e1 && r1 < krem)) ? v[j].y : 0.f;
            o.z = (v[j].z > fT || (e2 && r2 < krem)) ? v[j].z : 0.f;
            o.w = (v[j].w > fT || (e3 && r3 < krem)) ? v[j].w : 0.f;
            orow[tid + j*TPB] = o;
            runacc += total;
        }
    }
}

extern "C" void kernel_launch(void* const* d_in, const int* in_sizes, int n_in,
                              void* d_out, int out_size, void* d_ws, size_t ws_size,
                              hipStream_t stream) {
    const float* x = (const float*)d_in[0];
    float* out = (float*)d_out;
    const int B = in_sizes[0] / NCOL;   // 4096 rows
    topk_act_kernel<<<B, TPB, 0, stream>>>(x, out);
}

// Round 12
// 112.184 us; speedup vs baseline: 1.3918x; 1.3000x over previous
//
#include <hip/hip_runtime.h>

#define KTOP 100
#define NCOL 16384
#define TPB  1024
#define NCHUNK 4                 // 4 float4 (16 values) per thread, in registers (fits 32-VGPR budget)
#define HST  520                 // per-copy hist stride (512 words + 8 pad)
#define CAPB 512                 // boundary-bin candidate capacity
#define RB0  512u                // __float_as_uint(2.0f) >> 21

// order-preserving key transform (generic fallback only)
__device__ __forceinline__ unsigned enc(unsigned u){ return u ^ (((unsigned)((int)u>>31)) | 0x80000000u); }
__device__ __forceinline__ unsigned dec(unsigned k){ return k ^ ((k & 0x80000000u) ? 0x80000000u : 0xFFFFFFFFu); }
// transposed hist word index: scan's per-lane 8 reads land at stride-64 words -> conflict-free
__device__ __forceinline__ int hw(unsigned b){ return (int)(((b & 7u) << 6) | (b >> 3)); }

__global__ __launch_bounds__(TPB, 8)
void topk_act_kernel(const float* __restrict__ x, float* __restrict__ out) {
    __shared__ unsigned hist[2*HST];     // 2 wave-group copies (4.2 KB); tie path reuses as scan space
    __shared__ unsigned cand[CAPB];      // boundary candidates / generic-path 256-bin hist
    __shared__ unsigned s_pos, s_cnt, s_T, s_krem, s_eqc;

    const int tid = threadIdx.x, lane = tid & 63, wv = tid >> 6;
    const int row = blockIdx.x;
    const float4* __restrict__ xr = (const float4*)(x + (size_t)row * NCOL);
    float4* __restrict__ orow = (float4*)(out + (size_t)row * NCOL);

    for (int i = tid; i < 2*HST; i += TPB) hist[i] = 0;
    if (tid == 0) { s_pos = 0; s_cnt = 0; }
    __syncthreads();

    // ---- single HBM read -> registers (raw floats); hist only values >= 2.0 (~373/row) ----
    float4 v[NCHUNK];
    #pragma unroll
    for (int j = 0; j < NCHUNK; ++j) v[j] = xr[tid + j*TPB];   // all loads issued first
    unsigned* hb = hist + (wv & 1) * HST;
    unsigned pc = 0;
    #pragma unroll
    for (int j = 0; j < NCHUNK; ++j) {
        if (v[j].x >= 2.0f) { atomicAdd(&hb[hw((__float_as_uint(v[j].x)>>21)-RB0)],1u); ++pc; }
        if (v[j].y >= 2.0f) { atomicAdd(&hb[hw((__float_as_uint(v[j].y)>>21)-RB0)],1u); ++pc; }
        if (v[j].z >= 2.0f) { atomicAdd(&hb[hw((__float_as_uint(v[j].z)>>21)-RB0)],1u); ++pc; }
        if (v[j].w >= 2.0f) { atomicAdd(&hb[hw((__float_as_uint(v[j].w)>>21)-RB0)],1u); ++pc; }
    }
    #pragma unroll
    for (int s = 1; s < 64; s <<= 1) pc += __shfl_down(pc, s);
    if (lane == 0) atomicAdd(&s_pos, pc);
    __syncthreads();

    unsigned Traw, krem, eqv;
    bool ngen = false, have_local = false;
    if (s_pos >= KTOP) {
        // ---- wave-redundant suffix scan of 512 dual-copy bins (transposed, conflict-free) ----
        unsigned own = 0;
        #pragma unroll
        for (int w = 0; w < 8; ++w) own += hist[64*w + lane] + hist[HST + 64*w + lane];
        unsigned incl = own;
        #pragma unroll
        for (int s = 1; s < 64; s <<= 1) { unsigned t = __shfl_down(incl, s); if (lane + s < 64) incl += t; }
        const unsigned above = incl - own;
        bool hit = (above < KTOP) && (above + own >= KTOP);
        unsigned long long bal = __ballot(hit);
        int L = __ffsll((long long)bal) - 1;
        unsigned run = __shfl(above, L);
        unsigned sbin = 0, sk = 1, se = 1;
        for (int w = 7; w >= 0; --w) {
            unsigned c = hist[64*w + L] + hist[HST + 64*w + L];
            unsigned rr = run + c;
            if (run < KTOP && rr >= KTOP) { sbin = 8u*(unsigned)L + (unsigned)w; sk = KTOP - run; se = c; }
            run = rr;
        }
        const unsigned pbin = sbin + RB0;            // raw-bits bin (bits>>21) of boundary
        if (sk == se) {
            // K-boundary on bin edge: every thread knows T locally -> skip publish barriers
            Traw = pbin << 21; krem = sk; eqv = se; have_local = true;
        } else {
            // extract boundary-bin candidates (~2-8 for N(0,1)); raw bits, positives only match
            #pragma unroll
            for (int j = 0; j < NCHUNK; ++j) {
                if ((__float_as_uint(v[j].x)>>21) == pbin) { unsigned i = atomicAdd(&s_cnt,1u); if (i < CAPB) cand[i] = __float_as_uint(v[j].x); }
                if ((__float_as_uint(v[j].y)>>21) == pbin) { unsigned i = atomicAdd(&s_cnt,1u); if (i < CAPB) cand[i] = __float_as_uint(v[j].y); }
                if ((__float_as_uint(v[j].z)>>21) == pbin) { unsigned i = atomicAdd(&s_cnt,1u); if (i < CAPB) cand[i] = __float_as_uint(v[j].z); }
                if ((__float_as_uint(v[j].w)>>21) == pbin) { unsigned i = atomicAdd(&s_cnt,1u); if (i < CAPB) cand[i] = __float_as_uint(v[j].w); }
            }
            __syncthreads();
            const unsigned mcnt = s_cnt;
            if (mcnt <= CAPB) {
                if (tid < (int)mcnt) {               // all-pairs rank (uint order == float order, positives)
                    const unsigned c = cand[tid];
                    unsigned g = 0, q = 0;
                    for (unsigned jj = 0; jj < mcnt; ++jj) { unsigned cj = cand[jj]; g += (cj > c); q += (cj == c); }
                    if (g < sk && g + q >= sk) { s_T = c; s_krem = sk - g; s_eqc = q; }
                }
            } else ngen = true;
        }
    } else ngen = true;

    if (ngen) {
        // ---- rare generic 4x8-bit radix select (any distribution), enc keys on the fly ----
        unsigned pref = 0, kc = KTOP, eq = 0;
        for (int p = 0; p < 4; ++p) {
            const int shift = 24 - 8*p;
            __syncthreads();
            for (int i = tid; i < 256; i += TPB) cand[i] = 0;
            __syncthreads();
            #pragma unroll
            for (int j = 0; j < NCHUNK; ++j) {
                unsigned kk;
                kk = enc(__float_as_uint(v[j].x)); if (p == 0 || ((kk ^ pref) >> (shift+8)) == 0) atomicAdd(&cand[(kk >> shift) & 0xFFu], 1u);
                kk = enc(__float_as_uint(v[j].y)); if (p == 0 || ((kk ^ pref) >> (shift+8)) == 0) atomicAdd(&cand[(kk >> shift) & 0xFFu], 1u);
                kk = enc(__float_as_uint(v[j].z)); if (p == 0 || ((kk ^ pref) >> (shift+8)) == 0) atomicAdd(&cand[(kk >> shift) & 0xFFu], 1u);
                kk = enc(__float_as_uint(v[j].w)); if (p == 0 || ((kk ^ pref) >> (shift+8)) == 0) atomicAdd(&cand[(kk >> shift) & 0xFFu], 1u);
            }
            __syncthreads();
            unsigned t0 = cand[4*lane], t1 = cand[4*lane+1], t2 = cand[4*lane+2], t3 = cand[4*lane+3];
            unsigned own = t0+t1+t2+t3, incl = own;
            #pragma unroll
            for (int s = 1; s < 64; s <<= 1) { unsigned t = __shfl_down(incl, s); if (lane + s < 64) incl += t; }
            unsigned above = incl - own;
            unsigned C3 = above + t3, C2 = C3 + t2, C1 = C2 + t1, C0 = C1 + t0;
            bool h3 = (above < kc) && (C3 >= kc);
            bool h2 = (C3 < kc) && (C2 >= kc);
            bool h1 = (C2 < kc) && (C1 >= kc);
            bool h0 = (C1 < kc) && (C0 >= kc);
            unsigned mybin = h3 ? (4u*lane+3u) : h2 ? (4u*lane+2u) : h1 ? (4u*lane+1u) : (4u*lane);
            unsigned myk   = h3 ? (kc - above) : h2 ? (kc - C3) : h1 ? (kc - C2) : (kc - C1);
            unsigned myeq  = h3 ? t3 : h2 ? t2 : h1 ? t1 : t0;
            unsigned long long bal2 = __ballot(h0|h1|h2|h3);
            int L2 = __ffsll((long long)bal2) - 1;
            pref |= __shfl(mybin, L2) << shift;
            kc    = __shfl(myk, L2);
            eq    = __shfl(myeq, L2);
        }
        if (tid == 0) { s_T = dec(pref); s_krem = kc; s_eqc = eq; }  // publish raw float bits
    }
    if (!have_local) {
        __syncthreads();                             // publish fence (cand/generic paths)
        Traw = s_T; krem = s_krem; eqv = s_eqc;
    }

    const float fT = __uint_as_float(Traw);

    if (krem == eqv) {
        // ---- fast path: pure float compare, dense stores from registers ----
        #pragma unroll
        for (int j = 0; j < NCHUNK; ++j) {
            float4 o;
            o.x = (v[j].x >= fT) ? v[j].x : 0.f;
            o.y = (v[j].y >= fT) ? v[j].y : 0.f;
            o.z = (v[j].z >= fT) ? v[j].z : 0.f;
            o.w = (v[j].w >= fT) ? v[j].w : 0.f;
            orow[tid + j*TPB] = o;
        }
    } else {
        // ---- rare stable tie path: keep first krem equals in column order ----
        unsigned* sa = hist;                          // 1040 words >= TPB scan space
        unsigned runacc = 0;
        for (int j = 0; j < NCHUNK; ++j) {
            unsigned e0 = (v[j].x == fT), e1 = (v[j].y == fT), e2 = (v[j].z == fT), e3 = (v[j].w == fT);
            unsigned le = e0+e1+e2+e3;
            __syncthreads();
            sa[tid] = le;
            __syncthreads();
            for (int s = 1; s < TPB; s <<= 1) {
                unsigned t = (tid >= s) ? sa[tid-s] : 0u;
                __syncthreads();
                sa[tid] += t;
                __syncthreads();
            }
            unsigned excl = sa[tid] - le, total = sa[TPB-1];
            unsigned r0 = runacc + excl, r1 = r0+e0, r2 = r1+e1, r3 = r2+e2;
            float4 o;
            o.x = (v[j].x > fT || (e0 && r0 < krem)) ? v[j].x : 0.f;
            o.y = (v[j].y > fT || (e1 && r1 < krem)) ? v[j].y : 0.f;
            o.z = (v[j].z > fT || (e2 && r2 < krem)) ? v[j].z : 0.f;
            o.w = (v[j].w > fT || (e3 && r3 < krem)) ? v[j].w : 0.f;
            orow[tid + j*TPB] = o;
            runacc += total;
        }
    }
}

extern "C" void kernel_launch(void* const* d_in, const int* in_sizes, int n_in,
                              void* d_out, int out_size, void* d_ws, size_t ws_size,
                              hipStream_t stream) {
    const float* x = (const float*)d_in[0];
    float* out = (float*)d_out;
    const int B = in_sizes[0] / NCOL;   // 4096 rows
    topk_act_kernel<<<B, TPB, 0, stream>>>(x, out);
}